// Round 16
// baseline (188.789 us; speedup 1.0000x reference)
//
#include <hip/hip_runtime.h>
#include <hip/hip_fp16.h>

#define CH 256
#define HW 4096
#define K_TOP 115
#define CAND 128
#define CSTRIDE 4104  // u16/column: 4096 + 8 pad; 8208B row, 16B-aligned

typedef __attribute__((ext_vector_type(8))) short short8;
typedef __attribute__((ext_vector_type(4))) float f32x4;
typedef __attribute__((ext_vector_type(4))) unsigned int u32x4;

__device__ __forceinline__ unsigned short f32_to_bf16(float f) {
  union { float f; unsigned int u; } v; v.f = f;
  unsigned int r = v.u + 0x7fffu + ((v.u >> 16) & 1u);
  return (unsigned short)(r >> 16);
}

__device__ __forceinline__ unsigned int f16key(unsigned short h) {
  return (h & 0x8000u) ? (unsigned int)((unsigned short)~h)
                       : (unsigned int)(h | 0x8000u);
}

__device__ __forceinline__ unsigned short key2f16(unsigned int k) {
  return (k & 0x8000u) ? (unsigned short)(k ^ 0x8000u)
                       : (unsigned short)(~k & 0xffffu);
}

// ---------- kernel 1a: rn[b][p] = 1 / max(||x[b,:,p]||, eps) ----------
__global__ void norms_kernel(const float* __restrict__ x, float* __restrict__ rn) {
  int b = blockIdx.x >> 4;
  int p = ((blockIdx.x & 15) << 8) + threadIdx.x;
  const float* xb = x + (size_t)b * CH * HW + p;
  float ss = 0.f;
  #pragma unroll 8
  for (int c = 0; c < CH; ++c) { float v = xb[(size_t)c * HW]; ss += v * v; }
  rn[b * HW + p] = 1.0f / fmaxf(sqrtf(ss), 1e-12f);
}

// ---------- kernel 1b: xnT in FRAGMENT-MAJOR layout ----------
// xnT[b][pg:256][kk:8][lane:64] = 16B entry: pixel pg*16+(lane&15),
// channels kk*32+(lane>>4)*8 .. +8, bf16. Fragment load = 64 lanes x 16B
// CONTIGUOUS (1KB) — R14 proved this fixes the TA-bound GEMM (87.5->~40us).
__global__ void transpose_kernel(const float* __restrict__ x, const float* __restrict__ rn,
                                 unsigned short* __restrict__ xnT) {
  __shared__ float tile[64][65];   // [c_local][p_local]
  int blk = blockIdx.x;
  int b = blk >> 8;
  int rem = blk & 255;
  int c0 = (rem >> 6) << 6;
  int p0 = (rem & 63) << 6;
  for (int idx = threadIdx.x; idx < 64 * 64; idx += blockDim.x) {
    int c = idx >> 6, p = idx & 63;
    tile[c][p] = x[((size_t)b * CH + c0 + c) * HW + p0 + p];
  }
  __syncthreads();
  for (int E = threadIdx.x; E < 512; E += blockDim.x) {
    int lr  = E & 15;
    int lk  = (E >> 4) & 3;
    int kkl = (E >> 6) & 1;
    int pgl = E >> 7;
    int pl = pgl * 16 + lr;
    int cl = kkl * 32 + lk * 8;
    float s = rn[b * HW + p0 + pl];
    unsigned int w0, w1, w2, w3;
    w0 = (unsigned int)f32_to_bf16(tile[cl + 0][pl] * s) |
         ((unsigned int)f32_to_bf16(tile[cl + 1][pl] * s) << 16);
    w1 = (unsigned int)f32_to_bf16(tile[cl + 2][pl] * s) |
         ((unsigned int)f32_to_bf16(tile[cl + 3][pl] * s) << 16);
    w2 = (unsigned int)f32_to_bf16(tile[cl + 4][pl] * s) |
         ((unsigned int)f32_to_bf16(tile[cl + 5][pl] * s) << 16);
    w3 = (unsigned int)f32_to_bf16(tile[cl + 6][pl] * s) |
         ((unsigned int)f32_to_bf16(tile[cl + 7][pl] * s) << 16);
    u32x4 w = {w0, w1, w2, w3};
    int pg  = (p0 >> 4) + pgl;
    int kkg = (c0 >> 5) + kkl;
    *(u32x4*)(xnT + ((((size_t)b * 256 + pg) * 8 + kkg) * 64 + lk * 16 + lr) * 8) = w;
  }
}

// ---------- fused kernel: 16 full columns per block; GEMM->LDS keys->SWAR select ----------
// R5 fused structure (correct, was TA-bound) + R14 fragment-major loads (TA fix)
// + R15 SWAR select from 32 packed regs. No gkeys materialization: kills the
// 256MB HBM round-trip and the gram/select phase serialization across kernels.
struct FS {
  unsigned short colkeys[16][CSTRIDE];  // 131.3 KB
  unsigned short cand[16][CAND];        // 4 KB
  unsigned int   rcnt[16][CAND];        // 8 KB
  unsigned int   cnt[16];
};

__launch_bounds__(1024, 1)
__global__ void fused_kernel(const unsigned short* __restrict__ xnT,
                             float* __restrict__ out) {
  __shared__ __align__(16) FS s;
  const int tid  = threadIdx.x;
  const int lane = tid & 63;
  const int w    = tid >> 6;   // 16 waves; wave w owns column j0+w in selection
  const int lr   = lane & 15;
  const int lk   = lane >> 4;

  // XCD swizzle: xcd = blk&7 -> batch xcd>>1; its 2MB panel stays L2-resident.
  const int blk = blockIdx.x;
  const int xcd = blk & 7;
  const int bb  = xcd >> 1;
  const int cg  = ((xcd & 1) << 7) + (blk >> 3);   // column-group [0,256)
  const int j0  = cg * 16;
  const short8* x8 = (const short8*)(xnT + (size_t)bb * HW * CH);

  // B fragments: the 16 columns' pixel-group cg (contiguous 1KB loads)
  short8 bfrag[8];
  #pragma unroll
  for (int kk = 0; kk < 8; ++kk)
    bfrag[kk] = x8[(size_t)(cg * 8 + kk) * 64 + lane];

  // GEMM: wave w sweeps pixel-groups pg = w, w+16, ... (16 i-tiles).
  // D (m89): lane holds D[row=lk*4+r][col=lr]; row -> i pixel, col -> j col.
  for (int t = 0; t < 16; ++t) {
    const int pg = w + 16 * t;
    f32x4 acc = {0.f, 0.f, 0.f, 0.f};
    #pragma unroll
    for (int kk = 0; kk < 8; ++kk) {
      short8 afrag = x8[(size_t)(pg * 8 + kk) * 64 + lane];
      acc = __builtin_amdgcn_mfma_f32_16x16x32_bf16(afrag, bfrag[kk], acc, 0, 0, 0);
    }
    unsigned long long k0 = f16key(__half_as_ushort(__float2half(acc[0])));
    unsigned long long k1 = f16key(__half_as_ushort(__float2half(acc[1])));
    unsigned long long k2 = f16key(__half_as_ushort(__float2half(acc[2])));
    unsigned long long k3 = f16key(__half_as_ushort(__float2half(acc[3])));
    *(unsigned long long*)&s.colkeys[lr][pg * 16 + lk * 4] =
        k0 | (k1 << 16) | (k2 << 32) | (k3 << 48);
  }
  __syncthreads();  // fence: ull writes -> u32x4 reads

  // ---- select: wave w owns column w; keys -> 32 packed regs (R11-proven) ----
  const u32x4* cp4 = (const u32x4*)&s.colkeys[w][0];
  u32x4 q0 = cp4[0 * 64 + lane], q1 = cp4[1 * 64 + lane];
  u32x4 q2 = cp4[2 * 64 + lane], q3 = cp4[3 * 64 + lane];
  u32x4 q4 = cp4[4 * 64 + lane], q5 = cp4[5 * 64 + lane];
  u32x4 q6 = cp4[6 * 64 + lane], q7 = cp4[7 * 64 + lane];

  // SWAR transform: corr in [-1.008,1.008] => 15-bit keys after -0x4000
  q0 = (q0 - 0x40004000u) | 0x80008000u;
  q1 = (q1 - 0x40004000u) | 0x80008000u;
  q2 = (q2 - 0x40004000u) | 0x80008000u;
  q3 = (q3 - 0x40004000u) | 0x80008000u;
  q4 = (q4 - 0x40004000u) | 0x80008000u;
  q5 = (q5 - 0x40004000u) | 0x80008000u;
  q6 = (q6 - 0x40004000u) | 0x80008000u;
  q7 = (q7 - 0x40004000u) | 0x80008000u;

  // binary search in 15-bit space: lo = max v with #{k15 >= v} >= 115
  unsigned int lo = 0;
  #pragma unroll 1
  for (int bit = 14; bit >= 0; --bit) {
    const unsigned int m  = lo | (1u << bit);
    const unsigned int mm = m * 0x10001u;
    int c = 0;
    #define CNTV(Q) \
      c += (int)__builtin_popcount((Q.x - mm) & 0x80008000u); \
      c += (int)__builtin_popcount((Q.y - mm) & 0x80008000u); \
      c += (int)__builtin_popcount((Q.z - mm) & 0x80008000u); \
      c += (int)__builtin_popcount((Q.w - mm) & 0x80008000u);
    CNTV(q0) CNTV(q1) CNTV(q2) CNTV(q3)
    CNTV(q4) CNTV(q5) CNTV(q6) CNTV(q7)
    #undef CNTV
    c += __shfl_xor(c, 1);
    c += __shfl_xor(c, 2);
    c += __shfl_xor(c, 4);
    c += __shfl_xor(c, 8);
    c += __shfl_xor(c, 16);
    c += __shfl_xor(c, 32);
    if (c >= K_TOP) lo = m;
  }

  // prefill candidates with threshold; zero rank-offset table
  s.cand[w][2 * lane]     = (unsigned short)lo;
  s.cand[w][2 * lane + 1] = (unsigned short)lo;
  s.rcnt[w][2 * lane]     = 0;
  s.rcnt[w][2 * lane + 1] = 0;
  if (lane == 0) s.cnt[w] = 0;

  // scatter strictly-greater 15-bit keys (<=114 guaranteed) — wave-local
  #define GATH(v)                                                \
    { unsigned int _v = (v);                                     \
      if (_v > lo) {                                             \
        unsigned int _p = atomicAdd(&s.cnt[w], 1u);              \
        s.cand[w][_p] = (unsigned short)_v;                      \
      } }
  #define GATH4(Q)                                               \
    GATH(Q.x & 0x7fffu) GATH((Q.x >> 16) & 0x7fffu)              \
    GATH(Q.y & 0x7fffu) GATH((Q.y >> 16) & 0x7fffu)              \
    GATH(Q.z & 0x7fffu) GATH((Q.z >> 16) & 0x7fffu)              \
    GATH(Q.w & 0x7fffu) GATH((Q.w >> 16) & 0x7fffu)
  GATH4(q0) GATH4(q1) GATH4(q2) GATH4(q3)
  GATH4(q4) GATH4(q5) GATH4(q6) GATH4(q7)
  #undef GATH4
  #undef GATH

  __syncthreads();  // fence: scatter stores visible before u32 re-read

  // strict-greater count g per candidate (SWAR vs broadcast LDS reads),
  // then dense unique ranks for tie groups via atomic offsets (R15-proven).
  unsigned int k0 = s.cand[w][2 * lane];
  unsigned int k1 = s.cand[w][2 * lane + 1];
  const unsigned int t0 = (k0 + 1u) * 0x10001u;
  const unsigned int t1 = (k1 + 1u) * 0x10001u;
  int g0 = 0, g1 = 0;
  {
    const u32x4* cv = (const u32x4*)&s.cand[w][0];
    #pragma unroll
    for (int r = 0; r < 16; ++r) {
      u32x4 p = cv[r];
      #define GCNT(W) { unsigned int Pt = (W) | 0x80008000u;                 \
        g0 += (int)__builtin_popcount((Pt - t0) & 0x80008000u);              \
        g1 += (int)__builtin_popcount((Pt - t1) & 0x80008000u); }
      GCNT(p.x) GCNT(p.y) GCNT(p.z) GCNT(p.w)
      #undef GCNT
    }
  }
  unsigned int o0 = atomicAdd(&s.rcnt[w][g0], 1u);
  unsigned int o1 = atomicAdd(&s.rcnt[w][g1], 1u);
  int r0 = g0 + (int)o0;
  int r1 = g1 + (int)o1;

  if (r0 < K_TOP)
    out[((size_t)bb * K_TOP + r0) * HW + j0 + w] =
        __half2float(__ushort_as_half(key2f16(k0 + 0x4000u))) * (1.0f / 256.0f);
  if (r1 < K_TOP)
    out[((size_t)bb * K_TOP + r1) * HW + j0 + w] =
        __half2float(__ushort_as_half(key2f16(k1 + 0x4000u))) * (1.0f / 256.0f);
}

extern "C" void kernel_launch(void* const* d_in, const int* in_sizes, int n_in,
                              void* d_out, int out_size, void* d_ws, size_t ws_size,
                              hipStream_t stream) {
  (void)in_sizes; (void)n_in; (void)out_size; (void)ws_size;
  const float* x = (const float*)d_in[0];
  float* out = (float*)d_out;
  float* rn = (float*)d_ws;                                       // 64 KB
  unsigned short* xnT = (unsigned short*)((char*)d_ws + 65536);   // 8 MB bf16

  norms_kernel<<<64, 256, 0, stream>>>(x, rn);
  transpose_kernel<<<1024, 256, 0, stream>>>(x, rn, xnT);
  fused_kernel<<<1024, 1024, 0, stream>>>(xnT, out);
}

// Round 17
// 170.712 us; speedup vs baseline: 1.1059x; 1.1059x over previous
//
#include <hip/hip_runtime.h>
#include <hip/hip_fp16.h>

#define CH 256
#define HW 4096
#define K_TOP 115
#define CAND 128
#define TPAD 152   // u16 row stride: 304B; 4-row offset = 16 mod 32 -> 2-way (free)
#define NTRI 528   // 32*33/2 upper-triangle 128x128 tiles per batch

typedef __attribute__((ext_vector_type(8))) short short8;
typedef __attribute__((ext_vector_type(4))) float f32x4;
typedef __attribute__((ext_vector_type(4))) unsigned int u32x4;

__device__ __forceinline__ unsigned short f32_to_bf16(float f) {
  union { float f; unsigned int u; } v; v.f = f;
  unsigned int r = v.u + 0x7fffu + ((v.u >> 16) & 1u);
  return (unsigned short)(r >> 16);
}

__device__ __forceinline__ unsigned int f16key(unsigned short h) {
  return (h & 0x8000u) ? (unsigned int)((unsigned short)~h)
                       : (unsigned int)(h | 0x8000u);
}

__device__ __forceinline__ unsigned short key2f16(unsigned int k) {
  return (k & 0x8000u) ? (unsigned short)(k ^ 0x8000u)
                       : (unsigned short)(~k & 0xffffu);
}

// ---------- kernel 1a: rn[b][p] = 1 / max(||x[b,:,p]||, eps) ----------
__global__ void norms_kernel(const float* __restrict__ x, float* __restrict__ rn) {
  int b = blockIdx.x >> 4;
  int p = ((blockIdx.x & 15) << 8) + threadIdx.x;
  const float* xb = x + (size_t)b * CH * HW + p;
  float ss = 0.f;
  #pragma unroll 8
  for (int c = 0; c < CH; ++c) { float v = xb[(size_t)c * HW]; ss += v * v; }
  rn[b * HW + p] = 1.0f / fmaxf(sqrtf(ss), 1e-12f);
}

// ---------- kernel 1b: xnT in FRAGMENT-MAJOR layout (R14: fixes TA-bound GEMM) ----------
__global__ void transpose_kernel(const float* __restrict__ x, const float* __restrict__ rn,
                                 unsigned short* __restrict__ xnT) {
  __shared__ float tile[64][65];   // [c_local][p_local]
  int blk = blockIdx.x;
  int b = blk >> 8;
  int rem = blk & 255;
  int c0 = (rem >> 6) << 6;
  int p0 = (rem & 63) << 6;
  for (int idx = threadIdx.x; idx < 64 * 64; idx += blockDim.x) {
    int c = idx >> 6, p = idx & 63;
    tile[c][p] = x[((size_t)b * CH + c0 + c) * HW + p0 + p];
  }
  __syncthreads();
  for (int E = threadIdx.x; E < 512; E += blockDim.x) {
    int lr  = E & 15;
    int lk  = (E >> 4) & 3;
    int kkl = (E >> 6) & 1;
    int pgl = E >> 7;
    int pl = pgl * 16 + lr;
    int cl = kkl * 32 + lk * 8;
    float s = rn[b * HW + p0 + pl];
    unsigned int w0, w1, w2, w3;
    w0 = (unsigned int)f32_to_bf16(tile[cl + 0][pl] * s) |
         ((unsigned int)f32_to_bf16(tile[cl + 1][pl] * s) << 16);
    w1 = (unsigned int)f32_to_bf16(tile[cl + 2][pl] * s) |
         ((unsigned int)f32_to_bf16(tile[cl + 3][pl] * s) << 16);
    w2 = (unsigned int)f32_to_bf16(tile[cl + 4][pl] * s) |
         ((unsigned int)f32_to_bf16(tile[cl + 5][pl] * s) << 16);
    w3 = (unsigned int)f32_to_bf16(tile[cl + 6][pl] * s) |
         ((unsigned int)f32_to_bf16(tile[cl + 7][pl] * s) << 16);
    u32x4 w = {w0, w1, w2, w3};
    int pg  = (p0 >> 4) + pgl;
    int kkg = (c0 >> 5) + kkl;
    *(u32x4*)(xnT + ((((size_t)b * 256 + pg) * 8 + kkg) * 64 + lk * 16 + lr) * 8) = w;
  }
}

// ---------- shared LDS shapes ----------
struct SelS {
  unsigned short cand[4][CAND];
  unsigned int   rcnt[4][CAND];
  unsigned int   cnt[4];
};
union MixS {
  unsigned short tile[128 * TPAD];  // 38912 B (gram role)
  SelS sel;                         // 3088 B  (select role)
};

// ---------- gram body: one 128x128 symmetric Gram tile -> u16 keys ----------
__device__ __forceinline__ void gram_body(unsigned short* tile,
                                          const unsigned short* __restrict__ xnTb,
                                          unsigned short* __restrict__ gk,
                                          int t, int tid) {
  const int lane = tid & 63, wv = tid >> 6;
  const int wj = wv >> 1, wi = wv & 1;
  const int lr = lane & 15, lk = lane >> 4;

  int it = (int)((sqrtf(8.0f * (float)t + 1.0f) - 1.0f) * 0.5f);
  while (((it + 1) * (it + 2)) / 2 <= t) ++it;
  while ((it * (it + 1)) / 2 > t) --it;
  const int jt = t - (it * (it + 1)) / 2;  // jt <= it
  const int j0 = jt * 128, i0 = it * 128;
  const short8* x8 = (const short8*)xnTb;

  f32x4 acc[4][4];
  #pragma unroll
  for (int m = 0; m < 4; ++m)
    #pragma unroll
    for (int n = 0; n < 4; ++n) acc[m][n] = (f32x4){0.f, 0.f, 0.f, 0.f};

  // fragment-major: entry ((pg*8 + kk)*64 + lane), pg = pixel/16
  const int pgj = jt * 8 + wj * 4;
  const int pgi = it * 8 + wi * 4;
  #pragma unroll
  for (int kk = 0; kk < 8; ++kk) {
    short8 af[4], bf[4];
    #pragma unroll
    for (int m = 0; m < 4; ++m)
      af[m] = x8[(size_t)((pgj + m) * 8 + kk) * 64 + lane];
    #pragma unroll
    for (int n = 0; n < 4; ++n)
      bf[n] = x8[(size_t)((pgi + n) * 8 + kk) * 64 + lane];
    #pragma unroll
    for (int m = 0; m < 4; ++m)
      #pragma unroll
      for (int n = 0; n < 4; ++n)
        acc[m][n] = __builtin_amdgcn_mfma_f32_16x16x32_bf16(af[m], bf[n],
                                                            acc[m][n], 0, 0, 0);
  }

  // phase 1: keys -> tile[jloc][iloc]  (D row = j, D col = i)
  #pragma unroll
  for (int m = 0; m < 4; ++m) {
    #pragma unroll
    for (int n = 0; n < 4; ++n) {
      #pragma unroll
      for (int r = 0; r < 4; ++r) {
        int jloc = wj * 64 + m * 16 + lk * 4 + r;
        int iloc = wi * 64 + n * 16 + lr;
        tile[jloc * TPAD + iloc] =
            (unsigned short)f16key(__half_as_ushort(__float2half(acc[m][n][r])));
      }
    }
  }
  __syncthreads();

  // store 1: rows j of gk
  #pragma unroll
  for (int itr = 0; itr < 8; ++itr) {
    int idx = itr * 256 + tid;
    int row = idx >> 4, ch = idx & 15;
    u32x4 v = *(const u32x4*)&tile[row * TPAD + ch * 8];
    *(u32x4*)(gk + (size_t)(j0 + row) * HW + i0 + ch * 8) = v;
  }

  if (it != jt) {
    __syncthreads();  // WAR: store-1 reads done before refill
    #pragma unroll
    for (int m = 0; m < 4; ++m) {
      #pragma unroll
      for (int n = 0; n < 4; ++n) {
        int il  = wi * 64 + n * 16 + lr;
        int jl0 = wj * 64 + m * 16 + lk * 4;
        unsigned long long pk =
            (unsigned long long)f16key(__half_as_ushort(__float2half(acc[m][n][0]))) |
            ((unsigned long long)f16key(__half_as_ushort(__float2half(acc[m][n][1]))) << 16) |
            ((unsigned long long)f16key(__half_as_ushort(__float2half(acc[m][n][2]))) << 32) |
            ((unsigned long long)f16key(__half_as_ushort(__float2half(acc[m][n][3]))) << 48);
        *(unsigned long long*)&tile[il * TPAD + jl0] = pk;
      }
    }
    __syncthreads();

    // store 2: mirror rows i of gk
    #pragma unroll
    for (int itr = 0; itr < 8; ++itr) {
      int idx = itr * 256 + tid;
      int row = idx >> 4, ch = idx & 15;
      u32x4 v = *(const u32x4*)&tile[row * TPAD + ch * 8];
      *(u32x4*)(gk + (size_t)(i0 + row) * HW + j0 + ch * 8) = v;
    }
  }
}

// ---------- select body: 4 columns per block (1/wave), SWAR search + O(1) rank ----------
__device__ __forceinline__ void select_body(SelS* s,
                                            const unsigned short* __restrict__ gkb,
                                            float* __restrict__ out,
                                            int b, int cg, int tid) {
  const int lane = tid & 63, wv = tid >> 6;
  const int j = cg * 4 + wv;

  const u32x4* cp4 = (const u32x4*)(gkb + (size_t)j * HW);
  u32x4 q0 = cp4[0 * 64 + lane], q1 = cp4[1 * 64 + lane];
  u32x4 q2 = cp4[2 * 64 + lane], q3 = cp4[3 * 64 + lane];
  u32x4 q4 = cp4[4 * 64 + lane], q5 = cp4[5 * 64 + lane];
  u32x4 q6 = cp4[6 * 64 + lane], q7 = cp4[7 * 64 + lane];

  // SWAR transform: corr in [-1.008,1.008] => 15-bit keys after -0x4000
  q0 = (q0 - 0x40004000u) | 0x80008000u;
  q1 = (q1 - 0x40004000u) | 0x80008000u;
  q2 = (q2 - 0x40004000u) | 0x80008000u;
  q3 = (q3 - 0x40004000u) | 0x80008000u;
  q4 = (q4 - 0x40004000u) | 0x80008000u;
  q5 = (q5 - 0x40004000u) | 0x80008000u;
  q6 = (q6 - 0x40004000u) | 0x80008000u;
  q7 = (q7 - 0x40004000u) | 0x80008000u;

  // binary search in 15-bit space: lo = max v with #{k15 >= v} >= 115
  unsigned int lo = 0;
  #pragma unroll 1
  for (int bit = 14; bit >= 0; --bit) {
    const unsigned int m  = lo | (1u << bit);
    const unsigned int mm = m * 0x10001u;
    int c = 0;
    #define CNTV(Q) \
      c += (int)__builtin_popcount((Q.x - mm) & 0x80008000u); \
      c += (int)__builtin_popcount((Q.y - mm) & 0x80008000u); \
      c += (int)__builtin_popcount((Q.z - mm) & 0x80008000u); \
      c += (int)__builtin_popcount((Q.w - mm) & 0x80008000u);
    CNTV(q0) CNTV(q1) CNTV(q2) CNTV(q3)
    CNTV(q4) CNTV(q5) CNTV(q6) CNTV(q7)
    #undef CNTV
    c += __shfl_xor(c, 1);
    c += __shfl_xor(c, 2);
    c += __shfl_xor(c, 4);
    c += __shfl_xor(c, 8);
    c += __shfl_xor(c, 16);
    c += __shfl_xor(c, 32);
    if (c >= K_TOP) lo = m;
  }

  // prefill candidates with threshold; zero rank-offset table
  s->cand[wv][2 * lane]     = (unsigned short)lo;
  s->cand[wv][2 * lane + 1] = (unsigned short)lo;
  s->rcnt[wv][2 * lane]     = 0;
  s->rcnt[wv][2 * lane + 1] = 0;
  if (lane == 0) s->cnt[wv] = 0;

  // scatter strictly-greater 15-bit keys (<=114 guaranteed)
  #define GATH(v)                                                \
    { unsigned int _v = (v);                                     \
      if (_v > lo) {                                             \
        unsigned int _p = atomicAdd(&s->cnt[wv], 1u);            \
        s->cand[wv][_p] = (unsigned short)_v;                    \
      } }
  #define GATH4(Q)                                               \
    GATH(Q.x & 0x7fffu) GATH((Q.x >> 16) & 0x7fffu)              \
    GATH(Q.y & 0x7fffu) GATH((Q.y >> 16) & 0x7fffu)              \
    GATH(Q.z & 0x7fffu) GATH((Q.z >> 16) & 0x7fffu)              \
    GATH(Q.w & 0x7fffu) GATH((Q.w >> 16) & 0x7fffu)
  GATH4(q0) GATH4(q1) GATH4(q2) GATH4(q3)
  GATH4(q4) GATH4(q5) GATH4(q6) GATH4(q7)
  #undef GATH4
  #undef GATH

  __syncthreads();  // fence: scatter stores visible before u32 re-read

  // strict-greater count g per candidate (SWAR, broadcast LDS reads),
  // dense unique ranks for ties via atomic offsets (R15-proven).
  unsigned int k0 = s->cand[wv][2 * lane];
  unsigned int k1 = s->cand[wv][2 * lane + 1];
  const unsigned int t0 = (k0 + 1u) * 0x10001u;
  const unsigned int t1 = (k1 + 1u) * 0x10001u;
  int g0 = 0, g1 = 0;
  {
    const u32x4* cv = (const u32x4*)&s->cand[wv][0];
    #pragma unroll
    for (int r = 0; r < 16; ++r) {
      u32x4 p = cv[r];
      #define GCNT(W) { unsigned int Pt = (W) | 0x80008000u;                 \
        g0 += (int)__builtin_popcount((Pt - t0) & 0x80008000u);              \
        g1 += (int)__builtin_popcount((Pt - t1) & 0x80008000u); }
      GCNT(p.x) GCNT(p.y) GCNT(p.z) GCNT(p.w)
      #undef GCNT
    }
  }
  unsigned int o0 = atomicAdd(&s->rcnt[wv][g0], 1u);
  unsigned int o1 = atomicAdd(&s->rcnt[wv][g1], 1u);
  int r0 = g0 + (int)o0;
  int r1 = g1 + (int)o1;

  if (r0 < K_TOP)
    out[((size_t)b * K_TOP + r0) * HW + j] =
        __half2float(__ushort_as_half(key2f16(k0 + 0x4000u))) * (1.0f / 256.0f);
  if (r1 < K_TOP)
    out[((size_t)b * K_TOP + r1) * HW + j] =
        __half2float(__ushort_as_half(key2f16(k1 + 0x4000u))) * (1.0f / 256.0f);
}

// ---------- standalone kernels ----------
__launch_bounds__(256, 4)
__global__ void gram_kernel(const unsigned short* __restrict__ xnTb,
                            unsigned short* __restrict__ gk) {
  __shared__ __align__(16) MixS ms;
  gram_body(ms.tile, xnTb, gk, blockIdx.x, threadIdx.x);
}

__launch_bounds__(256, 4)
__global__ void select_kernel(const unsigned short* __restrict__ gkb,
                              float* __restrict__ out, int b) {
  __shared__ __align__(16) SelS ss;
  select_body(&ss, gkb, out, b, blockIdx.x, threadIdx.x);
}

// ---------- mixed-role pipeline kernel: gram(bg) || select(bs) ----------
// Roles interleaved by blockIdx%3 so both co-reside on every CU: gram blocks
// are memory/TA-bound (VALU ~11%), select blocks VALU-bound (86%) — the
// scheduler overlaps the pipes. No intra-kernel dependency (bg != bs).
__launch_bounds__(256, 4)
__global__ void mix_kernel(const unsigned short* __restrict__ xnT,
                           unsigned short* __restrict__ gk_g,
                           const unsigned short* __restrict__ gk_s,
                           float* __restrict__ out, int bg, int bs) {
  __shared__ __align__(16) MixS ms;
  const int blk = blockIdx.x;
  const int r3 = blk % 3;
  if (r3 == 0) {
    gram_body(ms.tile, xnT + (size_t)bg * HW * CH, gk_g, blk / 3, threadIdx.x);
  } else {
    int sidx = (blk / 3) * 2 + r3 - 1;   // [0,1056); 1024 used
    if (sidx < 1024)
      select_body(&ms.sel, gk_s, out, bs, sidx, threadIdx.x);
  }
}

extern "C" void kernel_launch(void* const* d_in, const int* in_sizes, int n_in,
                              void* d_out, int out_size, void* d_ws, size_t ws_size,
                              hipStream_t stream) {
  (void)in_sizes; (void)n_in; (void)out_size;
  const float* x = (const float*)d_in[0];
  float* out = (float*)d_out;
  float* rn = (float*)d_ws;                                       // 64 KB
  unsigned short* xnT = (unsigned short*)((char*)d_ws + 65536);   // 8 MB bf16
  const size_t GK_OFF   = 65536 + (size_t)8 * 1024 * 1024;
  const size_t ONE      = (size_t)HW * HW * 2;                    // 32 MB / batch
  const size_t NEED_SEQ = GK_OFF + ONE;                           // 40 MB
  const size_t NEED_PIPE = GK_OFF + 2 * ONE;                      // 72 MB

  norms_kernel<<<64, 256, 0, stream>>>(x, rn);
  transpose_kernel<<<1024, 256, 0, stream>>>(x, rn, xnT);

  if (ws_size >= NEED_PIPE) {
    unsigned short* gk0 = (unsigned short*)((char*)d_ws + GK_OFF);
    unsigned short* gk1 = gk0 + (size_t)HW * HW;
    // pipeline: gram(b) in dispatch k overlaps select(b-1) in the same dispatch
    gram_kernel<<<NTRI, 256, 0, stream>>>(xnT, gk0);
    mix_kernel<<<3 * NTRI, 256, 0, stream>>>(xnT, gk1, gk0, out, 1, 0);
    mix_kernel<<<3 * NTRI, 256, 0, stream>>>(xnT, gk0, gk1, out, 2, 1);
    mix_kernel<<<3 * NTRI, 256, 0, stream>>>(xnT, gk1, gk0, out, 3, 2);
    select_kernel<<<1024, 256, 0, stream>>>(gk1, out, 3);
  } else if (ws_size >= NEED_SEQ) {
    unsigned short* gk0 = (unsigned short*)((char*)d_ws + GK_OFF);
    for (int b = 0; b < 4; ++b) {
      gram_kernel<<<NTRI, 256, 0, stream>>>(xnT + (size_t)b * HW * CH, gk0);
      select_kernel<<<1024, 256, 0, stream>>>(gk0, out, b);
    }
  }
}

// Round 18
// 143.115 us; speedup vs baseline: 1.3191x; 1.1928x over previous
//
#include <hip/hip_runtime.h>
#include <hip/hip_fp16.h>

#define CH 256
#define HW 4096
#define K_TOP 115
#define CAND 128
#define TPAD 152   // u16 row stride: 304B = 19*16 (16B aligned); 4-row offset = 16 mod 32 -> 2-way (free)
#define NTRI 528   // 32*33/2 upper-triangle 128x128 tiles per batch
#define NTRI_H 264 // half-triangle per XCD

typedef __attribute__((ext_vector_type(8))) short short8;
typedef __attribute__((ext_vector_type(4))) float f32x4;
typedef __attribute__((ext_vector_type(4))) unsigned int u32x4;

__device__ __forceinline__ unsigned short f32_to_bf16(float f) {
  union { float f; unsigned int u; } v; v.f = f;
  unsigned int r = v.u + 0x7fffu + ((v.u >> 16) & 1u);
  return (unsigned short)(r >> 16);
}

__device__ __forceinline__ unsigned int f16key(unsigned short h) {
  return (h & 0x8000u) ? (unsigned int)((unsigned short)~h)
                       : (unsigned int)(h | 0x8000u);
}

// stored form: P = f16key + 0x4000 = (key15 | 0x8000), key15 = f16key - 0x4000.
// (f16key in [0x43F0,0xBC10] since |corr| <= 1.008, so no wrap; bit15 always set.)
__device__ __forceinline__ unsigned int f16keyP(unsigned short h) {
  return (f16key(h) + 0x4000u) & 0xffffu;
}

__device__ __forceinline__ unsigned short key2f16(unsigned int k) {
  return (k & 0x8000u) ? (unsigned short)(k ^ 0x8000u)
                       : (unsigned short)(~k & 0xffffu);
}

// ---------- kernel 1a: rn[b][p] = 1 / max(||x[b,:,p]||, eps) ----------
__global__ void norms_kernel(const float* __restrict__ x, float* __restrict__ rn) {
  int b = blockIdx.x >> 4;
  int p = ((blockIdx.x & 15) << 8) + threadIdx.x;
  const float* xb = x + (size_t)b * CH * HW + p;
  float ss = 0.f;
  #pragma unroll 8
  for (int c = 0; c < CH; ++c) { float v = xb[(size_t)c * HW]; ss += v * v; }
  rn[b * HW + p] = 1.0f / fmaxf(sqrtf(ss), 1e-12f);
}

// ---------- kernel 1b: xnT in FRAGMENT-MAJOR layout (R14: fixes TA-bound GEMM) ----------
__global__ void transpose_kernel(const float* __restrict__ x, const float* __restrict__ rn,
                                 unsigned short* __restrict__ xnT) {
  __shared__ float tile[64][65];   // [c_local][p_local]
  int blk = blockIdx.x;
  int b = blk >> 8;
  int rem = blk & 255;
  int c0 = (rem >> 6) << 6;
  int p0 = (rem & 63) << 6;
  for (int idx = threadIdx.x; idx < 64 * 64; idx += blockDim.x) {
    int c = idx >> 6, p = idx & 63;
    tile[c][p] = x[((size_t)b * CH + c0 + c) * HW + p0 + p];
  }
  __syncthreads();
  for (int E = threadIdx.x; E < 512; E += blockDim.x) {
    int lr  = E & 15;
    int lk  = (E >> 4) & 3;
    int kkl = (E >> 6) & 1;
    int pgl = E >> 7;
    int pl = pgl * 16 + lr;
    int cl = kkl * 32 + lk * 8;
    float s = rn[b * HW + p0 + pl];
    unsigned int w0, w1, w2, w3;
    w0 = (unsigned int)f32_to_bf16(tile[cl + 0][pl] * s) |
         ((unsigned int)f32_to_bf16(tile[cl + 1][pl] * s) << 16);
    w1 = (unsigned int)f32_to_bf16(tile[cl + 2][pl] * s) |
         ((unsigned int)f32_to_bf16(tile[cl + 3][pl] * s) << 16);
    w2 = (unsigned int)f32_to_bf16(tile[cl + 4][pl] * s) |
         ((unsigned int)f32_to_bf16(tile[cl + 5][pl] * s) << 16);
    w3 = (unsigned int)f32_to_bf16(tile[cl + 6][pl] * s) |
         ((unsigned int)f32_to_bf16(tile[cl + 7][pl] * s) << 16);
    u32x4 w = {w0, w1, w2, w3};
    int pg  = (p0 >> 4) + pgl;
    int kkg = (c0 >> 5) + kkl;
    *(u32x4*)(xnT + ((((size_t)b * 256 + pg) * 8 + kkg) * 64 + lk * 16 + lr) * 8) = w;
  }
}

// ---------- kernel A: symmetric Gram -> P-form u16 keys (row-major per batch) ----------
// 64-row LDS tile (19.4 KB) -> 8 blocks/CU (R12: gram latency-bound at 4 blocks).
// launch_bounds stays (256,4): R13 proved (256,8)'s 64-VGPR cap spills the
// 64-reg accumulator. Epilogue = R13's correctness-proven 2-pass half-tile.
__launch_bounds__(256, 4)
__global__ void gram_kernel(const unsigned short* __restrict__ xnT,
                            unsigned short* __restrict__ gkeys, int nb) {
  __shared__ unsigned short tile[64 * TPAD];
  const int tid  = threadIdx.x;
  const int lane = tid & 63, wv = tid >> 6;
  const int wj = wv >> 1, wi = wv & 1;
  const int lr = lane & 15, lk = lane >> 4;

  int bb, t;
  if (nb == 4) {
    const int xcd = blockIdx.x & 7;
    bb = xcd >> 1;
    t  = ((xcd & 1) ? NTRI_H : 0) + (blockIdx.x >> 3);
  } else {
    bb = 0;
    t  = blockIdx.x;
  }
  int it = (int)((sqrtf(8.0f * (float)t + 1.0f) - 1.0f) * 0.5f);
  while (((it + 1) * (it + 2)) / 2 <= t) ++it;
  while ((it * (it + 1)) / 2 > t) --it;
  const int jt = t - (it * (it + 1)) / 2;  // jt <= it
  const int j0 = jt * 128, i0 = it * 128;

  const short8* x8 = (const short8*)(xnT + (size_t)bb * HW * CH);
  unsigned short* gk = gkeys + (size_t)bb * HW * HW;

  f32x4 acc[4][4];
  #pragma unroll
  for (int m = 0; m < 4; ++m)
    #pragma unroll
    for (int n = 0; n < 4; ++n) acc[m][n] = (f32x4){0.f, 0.f, 0.f, 0.f};

  // fragment-major: entry ((pg*8 + kk)*64 + lane), pg = pixel/16
  const int pgj = jt * 8 + wj * 4;
  const int pgi = it * 8 + wi * 4;
  #pragma unroll
  for (int kk = 0; kk < 8; ++kk) {
    short8 af[4], bf[4];
    #pragma unroll
    for (int m = 0; m < 4; ++m)
      af[m] = x8[(size_t)((pgj + m) * 8 + kk) * 64 + lane];
    #pragma unroll
    for (int n = 0; n < 4; ++n)
      bf[n] = x8[(size_t)((pgi + n) * 8 + kk) * 64 + lane];
    #pragma unroll
    for (int m = 0; m < 4; ++m)
      #pragma unroll
      for (int n = 0; n < 4; ++n)
        acc[m][n] = __builtin_amdgcn_mfma_f32_16x16x32_bf16(af[m], bf[n],
                                                            acc[m][n], 0, 0, 0);
  }

  // ---- epilogue: half-tile passes through the 64-row buffer (R13-proven) ----
  #define WRITE_NORMAL(WJ)                                                     \
    if (wj == (WJ)) {                                                          \
      _Pragma("unroll")                                                        \
      for (int m = 0; m < 4; ++m) {                                            \
        _Pragma("unroll")                                                      \
        for (int n = 0; n < 4; ++n) {                                          \
          _Pragma("unroll")                                                    \
          for (int r = 0; r < 4; ++r) {                                        \
            int jloc = m * 16 + lk * 4 + r;                                    \
            int iloc = wi * 64 + n * 16 + lr;                                  \
            tile[jloc * TPAD + iloc] = (unsigned short)f16keyP(                \
                __half_as_ushort(__float2half(acc[m][n][r])));                 \
          }                                                                    \
        }                                                                      \
      }                                                                        \
    }
  #define WRITE_MIRROR(WI)                                                     \
    if (wi == (WI)) {                                                          \
      _Pragma("unroll")                                                        \
      for (int m = 0; m < 4; ++m) {                                            \
        _Pragma("unroll")                                                      \
        for (int n = 0; n < 4; ++n) {                                          \
          int il  = n * 16 + lr;                                               \
          int jl0 = wj * 64 + m * 16 + lk * 4;                                 \
          unsigned long long pk =                                              \
              (unsigned long long)f16keyP(__half_as_ushort(__float2half(acc[m][n][0]))) |        \
              ((unsigned long long)f16keyP(__half_as_ushort(__float2half(acc[m][n][1]))) << 16) |\
              ((unsigned long long)f16keyP(__half_as_ushort(__float2half(acc[m][n][2]))) << 32) |\
              ((unsigned long long)f16keyP(__half_as_ushort(__float2half(acc[m][n][3]))) << 48); \
          *(unsigned long long*)&tile[il * TPAD + jl0] = pk;                   \
        }                                                                      \
      }                                                                        \
    }
  #define STORE_HALF(RB, CB)                                                   \
    _Pragma("unroll")                                                          \
    for (int itr = 0; itr < 4; ++itr) {                                        \
      int idx = itr * 256 + tid;                                               \
      int row = idx >> 4, ch = idx & 15;                                       \
      u32x4 v = *(const u32x4*)&tile[row * TPAD + ch * 8];                     \
      *(u32x4*)(gk + (size_t)((RB) + row) * HW + (CB) + ch * 8) = v;           \
    }

  WRITE_NORMAL(0)
  __syncthreads();
  STORE_HALF(j0, i0)
  __syncthreads();
  WRITE_NORMAL(1)
  __syncthreads();
  STORE_HALF(j0 + 64, i0)

  if (it != jt) {
    __syncthreads();
    WRITE_MIRROR(0)
    __syncthreads();
    STORE_HALF(i0, j0)
    __syncthreads();
    WRITE_MIRROR(1)
    __syncthreads();
    STORE_HALF(i0 + 64, j0)
  }
  #undef WRITE_NORMAL
  #undef WRITE_MIRROR
  #undef STORE_HALF
}

// ---------- kernel B: per-column top-115, SWAR packed counting ----------
// Keys arrive PRE-TRANSFORMED (P-form: key15|0x8000 per half) — no transform
// pass. Round bit=14 peeled to a 2-op AND-count (m = 0x4000 is a single bit).
__launch_bounds__(256, 4)
__global__ void select_kernel(const unsigned short* __restrict__ gkeys,
                              float* __restrict__ out, int b_base, int nb) {
  __shared__ __align__(16) unsigned short cand[4][CAND];
  __shared__ unsigned int rcnt[4][CAND];
  __shared__ unsigned int cnt[4];
  const int tid  = threadIdx.x;
  const int lane = tid & 63, wv = tid >> 6;
  int bb, cg;
  if (nb == 4) {
    const int xcd = blockIdx.x & 7;
    bb = xcd >> 1;
    cg = ((xcd & 1) << 9) + (blockIdx.x >> 3);   // [0,1024)
  } else {
    bb = 0;
    cg = blockIdx.x;
  }
  const int b = b_base + bb;
  const int j = cg * 4 + wv;

  const u32x4* cp4 = (const u32x4*)(gkeys + (size_t)bb * HW * HW + (size_t)j * HW);
  u32x4 q0 = cp4[0 * 64 + lane], q1 = cp4[1 * 64 + lane];
  u32x4 q2 = cp4[2 * 64 + lane], q3 = cp4[3 * 64 + lane];
  u32x4 q4 = cp4[4 * 64 + lane], q5 = cp4[5 * 64 + lane];
  u32x4 q6 = cp4[6 * 64 + lane], q7 = cp4[7 * 64 + lane];

  unsigned int lo = 0;
  // peeled round bit=14: key15 >= 0x4000 <=> bit14 set (single-bit threshold)
  {
    int c = 0;
    #define CNTB(Q) \
      c += (int)__builtin_popcount(Q.x & 0x40004000u); \
      c += (int)__builtin_popcount(Q.y & 0x40004000u); \
      c += (int)__builtin_popcount(Q.z & 0x40004000u); \
      c += (int)__builtin_popcount(Q.w & 0x40004000u);
    CNTB(q0) CNTB(q1) CNTB(q2) CNTB(q3)
    CNTB(q4) CNTB(q5) CNTB(q6) CNTB(q7)
    #undef CNTB
    c += __shfl_xor(c, 1);
    c += __shfl_xor(c, 2);
    c += __shfl_xor(c, 4);
    c += __shfl_xor(c, 8);
    c += __shfl_xor(c, 16);
    c += __shfl_xor(c, 32);
    if (c >= K_TOP) lo = 0x4000u;
  }
  // remaining rounds: lo = max v with #{key15 >= v} >= 115 (borrow can't
  // cross halves: each P half >= 0x8000, m <= 0x7fff)
  #pragma unroll 1
  for (int bit = 13; bit >= 0; --bit) {
    const unsigned int m  = lo | (1u << bit);
    const unsigned int mm = m * 0x10001u;
    int c = 0;
    #define CNTV(Q) \
      c += (int)__builtin_popcount((Q.x - mm) & 0x80008000u); \
      c += (int)__builtin_popcount((Q.y - mm) & 0x80008000u); \
      c += (int)__builtin_popcount((Q.z - mm) & 0x80008000u); \
      c += (int)__builtin_popcount((Q.w - mm) & 0x80008000u);
    CNTV(q0) CNTV(q1) CNTV(q2) CNTV(q3)
    CNTV(q4) CNTV(q5) CNTV(q6) CNTV(q7)
    #undef CNTV
    c += __shfl_xor(c, 1);
    c += __shfl_xor(c, 2);
    c += __shfl_xor(c, 4);
    c += __shfl_xor(c, 8);
    c += __shfl_xor(c, 16);
    c += __shfl_xor(c, 32);
    if (c >= K_TOP) lo = m;
  }

  // prefill candidates with threshold; zero rank-offset table
  cand[wv][2 * lane]     = (unsigned short)lo;
  cand[wv][2 * lane + 1] = (unsigned short)lo;
  rcnt[wv][2 * lane]     = 0;
  rcnt[wv][2 * lane + 1] = 0;
  if (lane == 0) cnt[wv] = 0;

  // scatter strictly-greater 15-bit keys (<=114 guaranteed)
  #define GATH(v)                                                \
    { unsigned int _v = (v);                                     \
      if (_v > lo) {                                             \
        unsigned int _p = atomicAdd(&cnt[wv], 1u);               \
        cand[wv][_p] = (unsigned short)_v;                       \
      } }
  #define GATH4(Q)                                               \
    GATH(Q.x & 0x7fffu) GATH((Q.x >> 16) & 0x7fffu)              \
    GATH(Q.y & 0x7fffu) GATH((Q.y >> 16) & 0x7fffu)              \
    GATH(Q.z & 0x7fffu) GATH((Q.z >> 16) & 0x7fffu)              \
    GATH(Q.w & 0x7fffu) GATH((Q.w >> 16) & 0x7fffu)
  GATH4(q0) GATH4(q1) GATH4(q2) GATH4(q3)
  GATH4(q4) GATH4(q5) GATH4(q6) GATH4(q7)
  #undef GATH4
  #undef GATH

  __syncthreads();  // fence: scatter stores visible before u32 re-read

  // strict-greater count g per candidate (SWAR, broadcast LDS reads),
  // dense unique ranks for tie groups via atomic offsets (R15-proven).
  unsigned int k0 = cand[wv][2 * lane];
  unsigned int k1 = cand[wv][2 * lane + 1];
  const unsigned int t0 = (k0 + 1u) * 0x10001u;
  const unsigned int t1 = (k1 + 1u) * 0x10001u;
  int g0 = 0, g1 = 0;
  {
    const u32x4* cv = (const u32x4*)&cand[wv][0];
    #pragma unroll
    for (int r = 0; r < 16; ++r) {
      u32x4 p = cv[r];
      #define GCNT(W) { unsigned int Pt = (W) | 0x80008000u;                 \
        g0 += (int)__builtin_popcount((Pt - t0) & 0x80008000u);              \
        g1 += (int)__builtin_popcount((Pt - t1) & 0x80008000u); }
      GCNT(p.x) GCNT(p.y) GCNT(p.z) GCNT(p.w)
      #undef GCNT
    }
  }
  unsigned int o0 = atomicAdd(&rcnt[wv][g0], 1u);
  unsigned int o1 = atomicAdd(&rcnt[wv][g1], 1u);
  int r0 = g0 + (int)o0;
  int r1 = g1 + (int)o1;

  if (r0 < K_TOP)
    out[((size_t)b * K_TOP + r0) * HW + j] =
        __half2float(__ushort_as_half(key2f16(k0 + 0x4000u))) * (1.0f / 256.0f);
  if (r1 < K_TOP)
    out[((size_t)b * K_TOP + r1) * HW + j] =
        __half2float(__ushort_as_half(key2f16(k1 + 0x4000u))) * (1.0f / 256.0f);
}

extern "C" void kernel_launch(void* const* d_in, const int* in_sizes, int n_in,
                              void* d_out, int out_size, void* d_ws, size_t ws_size,
                              hipStream_t stream) {
  (void)in_sizes; (void)n_in; (void)out_size;
  const float* x = (const float*)d_in[0];
  float* out = (float*)d_out;
  float* rn = (float*)d_ws;                                       // 64 KB
  unsigned short* xnT = (unsigned short*)((char*)d_ws + 65536);   // 8 MB bf16
  const size_t GK_OFF = 65536 + (size_t)8 * 1024 * 1024;
  const size_t ONE    = (size_t)HW * HW * 2;                      // 32 MB / batch
  const size_t NEED_1 = GK_OFF + ONE;
  const size_t NEED_4 = GK_OFF + 4 * ONE;                         // 136 MB

  norms_kernel<<<64, 256, 0, stream>>>(x, rn);
  transpose_kernel<<<1024, 256, 0, stream>>>(x, rn, xnT);

  if (ws_size >= NEED_4) {
    unsigned short* gkeys = (unsigned short*)((char*)d_ws + GK_OFF);
    gram_kernel<<<4 * NTRI, 256, 0, stream>>>(xnT, gkeys, 4);
    select_kernel<<<4096, 256, 0, stream>>>(gkeys, out, 0, 4);
  } else if (ws_size >= NEED_1) {
    unsigned short* gkeys = (unsigned short*)((char*)d_ws + GK_OFF);
    for (int b = 0; b < 4; ++b) {
      gram_kernel<<<NTRI, 256, 0, stream>>>(xnT + (size_t)b * HW * CH, gkeys, 1);
      select_kernel<<<1024, 256, 0, stream>>>(gkeys, out, b, 1);
    }
  }
}

// Round 19
// 134.961 us; speedup vs baseline: 1.3988x; 1.0604x over previous
//
#include <hip/hip_runtime.h>
#include <hip/hip_fp16.h>

#define CH 256
#define HW 4096
#define K_TOP 115
#define CAND 128
#define TPAD 152   // u16 row stride: 304B; 4-row offset = 16 mod 32 -> 2-way (free)
#define NTRI 528   // 32*33/2 upper-triangle 128x128 tiles per batch
#define NTRI_H 264 // half-triangle per XCD

typedef __attribute__((ext_vector_type(8))) short short8;
typedef __attribute__((ext_vector_type(4))) float f32x4;
typedef __attribute__((ext_vector_type(4))) unsigned int u32x4;

__device__ __forceinline__ unsigned short f32_to_bf16(float f) {
  union { float f; unsigned int u; } v; v.f = f;
  unsigned int r = v.u + 0x7fffu + ((v.u >> 16) & 1u);
  return (unsigned short)(r >> 16);
}

__device__ __forceinline__ unsigned int f16key(unsigned short h) {
  return (h & 0x8000u) ? (unsigned int)((unsigned short)~h)
                       : (unsigned int)(h | 0x8000u);
}

// stored P-form: P = key15 | 0x8000, key15 = f16key - 0x4000 (no wrap:
// |corr|<=1.008 => f16key in [0x43F0,0xBC10]); bit15 always set.
__device__ __forceinline__ unsigned int f16keyP(unsigned short h) {
  return (f16key(h) + 0x4000u) & 0xffffu;
}

__device__ __forceinline__ unsigned short key2f16(unsigned int k) {
  return (k & 0x8000u) ? (unsigned short)(k ^ 0x8000u)
                       : (unsigned short)(~k & 0xffffu);
}

// ---------- kernel 1a: rn[b][p] = 1 / max(||x[b,:,p]||, eps) ----------
__global__ void norms_kernel(const float* __restrict__ x, float* __restrict__ rn) {
  int b = blockIdx.x >> 4;
  int p = ((blockIdx.x & 15) << 8) + threadIdx.x;
  const float* xb = x + (size_t)b * CH * HW + p;
  float ss = 0.f;
  #pragma unroll 8
  for (int c = 0; c < CH; ++c) { float v = xb[(size_t)c * HW]; ss += v * v; }
  rn[b * HW + p] = 1.0f / fmaxf(sqrtf(ss), 1e-12f);
}

// ---------- kernel 1b: xnT in FRAGMENT-MAJOR layout (R14: fixes TA-bound GEMM) ----------
__global__ void transpose_kernel(const float* __restrict__ x, const float* __restrict__ rn,
                                 unsigned short* __restrict__ xnT) {
  __shared__ float tile[64][65];   // [c_local][p_local]
  int blk = blockIdx.x;
  int b = blk >> 8;
  int rem = blk & 255;
  int c0 = (rem >> 6) << 6;
  int p0 = (rem & 63) << 6;
  for (int idx = threadIdx.x; idx < 64 * 64; idx += blockDim.x) {
    int c = idx >> 6, p = idx & 63;
    tile[c][p] = x[((size_t)b * CH + c0 + c) * HW + p0 + p];
  }
  __syncthreads();
  for (int E = threadIdx.x; E < 512; E += blockDim.x) {
    int lr  = E & 15;
    int lk  = (E >> 4) & 3;
    int kkl = (E >> 6) & 1;
    int pgl = E >> 7;
    int pl = pgl * 16 + lr;
    int cl = kkl * 32 + lk * 8;
    float s = rn[b * HW + p0 + pl];
    unsigned int w0, w1, w2, w3;
    w0 = (unsigned int)f32_to_bf16(tile[cl + 0][pl] * s) |
         ((unsigned int)f32_to_bf16(tile[cl + 1][pl] * s) << 16);
    w1 = (unsigned int)f32_to_bf16(tile[cl + 2][pl] * s) |
         ((unsigned int)f32_to_bf16(tile[cl + 3][pl] * s) << 16);
    w2 = (unsigned int)f32_to_bf16(tile[cl + 4][pl] * s) |
         ((unsigned int)f32_to_bf16(tile[cl + 5][pl] * s) << 16);
    w3 = (unsigned int)f32_to_bf16(tile[cl + 6][pl] * s) |
         ((unsigned int)f32_to_bf16(tile[cl + 7][pl] * s) << 16);
    u32x4 w = {w0, w1, w2, w3};
    int pg  = (p0 >> 4) + pgl;
    int kkg = (c0 >> 5) + kkl;
    *(u32x4*)(xnT + ((((size_t)b * 256 + pg) * 8 + kkg) * 64 + lk * 16 + lr) * 8) = w;
  }
}

// ---------- kernel A: symmetric Gram -> P-form u16 keys (R15 structure) ----------
// 128-row tile, 3 barriers. Gram is occupancy-pinned at 4 blocks/CU by its
// 128-reg/wave footprint (64 arch + 64 acc; R13/R18 evidence) — don't fight it.
__launch_bounds__(256, 4)
__global__ void gram_kernel(const unsigned short* __restrict__ xnT,
                            unsigned short* __restrict__ gkeys, int nb) {
  __shared__ unsigned short tile[128 * TPAD];
  const int tid  = threadIdx.x;
  const int lane = tid & 63, wv = tid >> 6;
  const int wj = wv >> 1, wi = wv & 1;
  const int lr = lane & 15, lk = lane >> 4;

  int bb, t;
  if (nb == 4) {
    const int xcd = blockIdx.x & 7;
    bb = xcd >> 1;
    t  = ((xcd & 1) ? NTRI_H : 0) + (blockIdx.x >> 3);
  } else {
    bb = 0;
    t  = blockIdx.x;
  }
  int it = (int)((sqrtf(8.0f * (float)t + 1.0f) - 1.0f) * 0.5f);
  while (((it + 1) * (it + 2)) / 2 <= t) ++it;
  while ((it * (it + 1)) / 2 > t) --it;
  const int jt = t - (it * (it + 1)) / 2;  // jt <= it
  const int j0 = jt * 128, i0 = it * 128;

  const short8* x8 = (const short8*)(xnT + (size_t)bb * HW * CH);
  unsigned short* gk = gkeys + (size_t)bb * HW * HW;

  f32x4 acc[4][4];
  #pragma unroll
  for (int m = 0; m < 4; ++m)
    #pragma unroll
    for (int n = 0; n < 4; ++n) acc[m][n] = (f32x4){0.f, 0.f, 0.f, 0.f};

  // fragment-major: entry ((pg*8 + kk)*64 + lane), pg = pixel/16
  const int pgj = jt * 8 + wj * 4;
  const int pgi = it * 8 + wi * 4;
  #pragma unroll
  for (int kk = 0; kk < 8; ++kk) {
    short8 af[4], bf[4];
    #pragma unroll
    for (int m = 0; m < 4; ++m)
      af[m] = x8[(size_t)((pgj + m) * 8 + kk) * 64 + lane];
    #pragma unroll
    for (int n = 0; n < 4; ++n)
      bf[n] = x8[(size_t)((pgi + n) * 8 + kk) * 64 + lane];
    #pragma unroll
    for (int m = 0; m < 4; ++m)
      #pragma unroll
      for (int n = 0; n < 4; ++n)
        acc[m][n] = __builtin_amdgcn_mfma_f32_16x16x32_bf16(af[m], bf[n],
                                                            acc[m][n], 0, 0, 0);
  }

  // phase 1: P-form keys -> tile[jloc][iloc]  (D row = j, D col = i)
  #pragma unroll
  for (int m = 0; m < 4; ++m) {
    #pragma unroll
    for (int n = 0; n < 4; ++n) {
      #pragma unroll
      for (int r = 0; r < 4; ++r) {
        int jloc = wj * 64 + m * 16 + lk * 4 + r;
        int iloc = wi * 64 + n * 16 + lr;
        tile[jloc * TPAD + iloc] =
            (unsigned short)f16keyP(__half_as_ushort(__float2half(acc[m][n][r])));
      }
    }
  }
  __syncthreads();

  // store 1: rows j of gk (coalesced 16B chunks)
  #pragma unroll
  for (int itr = 0; itr < 8; ++itr) {
    int idx = itr * 256 + tid;
    int row = idx >> 4, ch = idx & 15;
    u32x4 v = *(const u32x4*)&tile[row * TPAD + ch * 8];
    *(u32x4*)(gk + (size_t)(j0 + row) * HW + i0 + ch * 8) = v;
  }

  if (it != jt) {
    __syncthreads();  // WAR: store-1 reads done before refill
    #pragma unroll
    for (int m = 0; m < 4; ++m) {
      #pragma unroll
      for (int n = 0; n < 4; ++n) {
        int il  = wi * 64 + n * 16 + lr;
        int jl0 = wj * 64 + m * 16 + lk * 4;
        unsigned long long pk =
            (unsigned long long)f16keyP(__half_as_ushort(__float2half(acc[m][n][0]))) |
            ((unsigned long long)f16keyP(__half_as_ushort(__float2half(acc[m][n][1]))) << 16) |
            ((unsigned long long)f16keyP(__half_as_ushort(__float2half(acc[m][n][2]))) << 32) |
            ((unsigned long long)f16keyP(__half_as_ushort(__float2half(acc[m][n][3]))) << 48);
        *(unsigned long long*)&tile[il * TPAD + jl0] = pk;
      }
    }
    __syncthreads();

    // store 2: mirror rows i of gk
    #pragma unroll
    for (int itr = 0; itr < 8; ++itr) {
      int idx = itr * 256 + tid;
      int row = idx >> 4, ch = idx & 15;
      u32x4 v = *(const u32x4*)&tile[row * TPAD + ch * 8];
      *(u32x4*)(gk + (size_t)(i0 + row) * HW + j0 + ch * 8) = v;
    }
  }
}

// ---------- kernel B: per-column top-115, SWAR counting WITHOUT popcount ----------
// Hypothesis: v_bcnt (480/wave) issues at reduced rate and is the unexplained
// 2x in select's busy cycles. Masked values have bits only at 15/31, so
// accumulate (D>>15) as integers (bits land at 0 and 16; <=32 summands per
// half — no overflow) and fold once per round. Same op count, all full-rate.
__launch_bounds__(256, 4)
__global__ void select_kernel(const unsigned short* __restrict__ gkeys,
                              float* __restrict__ out, int b_base, int nb) {
  __shared__ __align__(16) unsigned short cand[4][CAND];
  __shared__ unsigned int rcnt[4][CAND];
  __shared__ unsigned int cnt[4];
  const int tid  = threadIdx.x;
  const int lane = tid & 63, wv = tid >> 6;
  int bb, cg;
  if (nb == 4) {
    const int xcd = blockIdx.x & 7;
    bb = xcd >> 1;
    cg = ((xcd & 1) << 9) + (blockIdx.x >> 3);   // [0,1024)
  } else {
    bb = 0;
    cg = blockIdx.x;
  }
  const int b = b_base + bb;
  const int j = cg * 4 + wv;

  const u32x4* cp4 = (const u32x4*)(gkeys + (size_t)bb * HW * HW + (size_t)j * HW);
  u32x4 q0 = cp4[0 * 64 + lane], q1 = cp4[1 * 64 + lane];
  u32x4 q2 = cp4[2 * 64 + lane], q3 = cp4[3 * 64 + lane];
  u32x4 q4 = cp4[4 * 64 + lane], q5 = cp4[5 * 64 + lane];
  u32x4 q6 = cp4[6 * 64 + lane], q7 = cp4[7 * 64 + lane];

  unsigned int lo = 0;
  // peeled round bit=14: key15 >= 0x4000 <=> bit14 set (single-bit mask)
  {
    unsigned int S = 0;
    #define CNTB(Q) \
      S += (Q.x >> 14) & 0x00010001u; \
      S += (Q.y >> 14) & 0x00010001u; \
      S += (Q.z >> 14) & 0x00010001u; \
      S += (Q.w >> 14) & 0x00010001u;
    CNTB(q0) CNTB(q1) CNTB(q2) CNTB(q3)
    CNTB(q4) CNTB(q5) CNTB(q6) CNTB(q7)
    #undef CNTB
    int c = (int)((S & 0xffffu) + (S >> 16));
    c += __shfl_xor(c, 1);
    c += __shfl_xor(c, 2);
    c += __shfl_xor(c, 4);
    c += __shfl_xor(c, 8);
    c += __shfl_xor(c, 16);
    c += __shfl_xor(c, 32);
    if (c >= K_TOP) lo = 0x4000u;
  }
  // remaining rounds: lo = max v with #{key15 >= v} >= 115. Borrow can't
  // cross halves (each P half >= 0x8000, m <= 0x7fff).
  #pragma unroll 1
  for (int bit = 13; bit >= 0; --bit) {
    const unsigned int m  = lo | (1u << bit);
    const unsigned int mm = m * 0x10001u;
    unsigned int S = 0;
    #define CNTV(Q) \
      S += ((Q.x - mm) >> 15) & 0x00010001u; \
      S += ((Q.y - mm) >> 15) & 0x00010001u; \
      S += ((Q.z - mm) >> 15) & 0x00010001u; \
      S += ((Q.w - mm) >> 15) & 0x00010001u;
    CNTV(q0) CNTV(q1) CNTV(q2) CNTV(q3)
    CNTV(q4) CNTV(q5) CNTV(q6) CNTV(q7)
    #undef CNTV
    int c = (int)((S & 0xffffu) + (S >> 16));
    c += __shfl_xor(c, 1);
    c += __shfl_xor(c, 2);
    c += __shfl_xor(c, 4);
    c += __shfl_xor(c, 8);
    c += __shfl_xor(c, 16);
    c += __shfl_xor(c, 32);
    if (c >= K_TOP) lo = m;
  }

  // prefill candidates with threshold; zero rank-offset table
  cand[wv][2 * lane]     = (unsigned short)lo;
  cand[wv][2 * lane + 1] = (unsigned short)lo;
  rcnt[wv][2 * lane]     = 0;
  rcnt[wv][2 * lane + 1] = 0;
  if (lane == 0) cnt[wv] = 0;

  // scatter strictly-greater 15-bit keys (<=114 guaranteed)
  #define GATH(v)                                                \
    { unsigned int _v = (v);                                     \
      if (_v > lo) {                                             \
        unsigned int _p = atomicAdd(&cnt[wv], 1u);               \
        cand[wv][_p] = (unsigned short)_v;                       \
      } }
  #define GATH4(Q)                                               \
    GATH(Q.x & 0x7fffu) GATH((Q.x >> 16) & 0x7fffu)              \
    GATH(Q.y & 0x7fffu) GATH((Q.y >> 16) & 0x7fffu)              \
    GATH(Q.z & 0x7fffu) GATH((Q.z >> 16) & 0x7fffu)              \
    GATH(Q.w & 0x7fffu) GATH((Q.w >> 16) & 0x7fffu)
  GATH4(q0) GATH4(q1) GATH4(q2) GATH4(q3)
  GATH4(q4) GATH4(q5) GATH4(q6) GATH4(q7)
  #undef GATH4
  #undef GATH

  __syncthreads();  // fence: scatter stores visible before u32 re-read

  // strict-greater count g per candidate (SWAR, broadcast LDS reads, no bcnt),
  // then dense unique ranks for tie groups via atomic offsets.
  unsigned int k0 = cand[wv][2 * lane];
  unsigned int k1 = cand[wv][2 * lane + 1];
  const unsigned int t0 = (k0 + 1u) * 0x10001u;
  const unsigned int t1 = (k1 + 1u) * 0x10001u;
  unsigned int S0 = 0, S1 = 0;
  {
    const u32x4* cv = (const u32x4*)&cand[wv][0];
    #pragma unroll
    for (int r = 0; r < 16; ++r) {
      u32x4 p = cv[r];
      #define GCNT(W) { unsigned int Pt = (W) | 0x80008000u;      \
        S0 += ((Pt - t0) >> 15) & 0x00010001u;                    \
        S1 += ((Pt - t1) >> 15) & 0x00010001u; }
      GCNT(p.x) GCNT(p.y) GCNT(p.z) GCNT(p.w)
      #undef GCNT
    }
  }
  int g0 = (int)((S0 & 0xffffu) + (S0 >> 16));
  int g1 = (int)((S1 & 0xffffu) + (S1 >> 16));
  unsigned int o0 = atomicAdd(&rcnt[wv][g0], 1u);
  unsigned int o1 = atomicAdd(&rcnt[wv][g1], 1u);
  int r0 = g0 + (int)o0;
  int r1 = g1 + (int)o1;

  if (r0 < K_TOP)
    out[((size_t)b * K_TOP + r0) * HW + j] =
        __half2float(__ushort_as_half(key2f16(k0 + 0x4000u))) * (1.0f / 256.0f);
  if (r1 < K_TOP)
    out[((size_t)b * K_TOP + r1) * HW + j] =
        __half2float(__ushort_as_half(key2f16(k1 + 0x4000u))) * (1.0f / 256.0f);
}

extern "C" void kernel_launch(void* const* d_in, const int* in_sizes, int n_in,
                              void* d_out, int out_size, void* d_ws, size_t ws_size,
                              hipStream_t stream) {
  (void)in_sizes; (void)n_in; (void)out_size;
  const float* x = (const float*)d_in[0];
  float* out = (float*)d_out;
  float* rn = (float*)d_ws;                                       // 64 KB
  unsigned short* xnT = (unsigned short*)((char*)d_ws + 65536);   // 8 MB bf16
  const size_t GK_OFF = 65536 + (size_t)8 * 1024 * 1024;
  const size_t ONE    = (size_t)HW * HW * 2;                      // 32 MB / batch
  const size_t NEED_1 = GK_OFF + ONE;
  const size_t NEED_4 = GK_OFF + 4 * ONE;                         // 136 MB

  norms_kernel<<<64, 256, 0, stream>>>(x, rn);
  transpose_kernel<<<1024, 256, 0, stream>>>(x, rn, xnT);

  if (ws_size >= NEED_4) {
    unsigned short* gkeys = (unsigned short*)((char*)d_ws + GK_OFF);
    gram_kernel<<<4 * NTRI, 256, 0, stream>>>(xnT, gkeys, 4);
    select_kernel<<<4096, 256, 0, stream>>>(gkeys, out, 0, 4);
  } else if (ws_size >= NEED_1) {
    unsigned short* gkeys = (unsigned short*)((char*)d_ws + GK_OFF);
    for (int b = 0; b < 4; ++b) {
      gram_kernel<<<NTRI, 256, 0, stream>>>(xnT + (size_t)b * HW * CH, gkeys, 1);
      select_kernel<<<1024, 256, 0, stream>>>(gkeys, out, b, 1);
    }
  }
}